// Round 1
// baseline (11121.967 us; speedup 1.0000x reference)
//
#include <hip/hip_runtime.h>
#include <hip/hip_bf16.h>

// LSTM: L=512 steps, N=64 batch, I=H=1024.
// Strategy:
//  K1: convert x (fp32->bf16) + h0->bf16 + init grid barrier.
//  K2: persistent fused recurrence. 128 WGs x 256 thr. WG g owns hidden units
//      [8g,8g+8) => 32 rows of combined weights [W_ih|W_hh] (4096x2048 view).
//      Each wave holds its K-quarter of those rows as MFMA A-fragments in
//      128 VGPRs (loaded once). Per step: MFMA over K, LDS cross-wave reduce,
//      gate math (c in per-thread regs), h -> bf16 double buffer, device-scope
//      barrier. Final h,c written fp32 to d_out.
//  K3: y = h @ W_out^T + b_out, one wave per output element.

#define L_STEPS 512
#define NB 64
#define HID 1024
#define GRID_LSTM 128

typedef __bf16 bf16x8 __attribute__((ext_vector_type(8)));
typedef __bf16 bf16x4 __attribute__((ext_vector_type(4)));
typedef __bf16 bf16x2 __attribute__((ext_vector_type(2)));
typedef float  f32x4  __attribute__((ext_vector_type(4)));
typedef float  f32x2  __attribute__((ext_vector_type(2)));

__device__ __forceinline__ float sigmoid_f(float x) {
    return 1.f / (1.f + __expf(-x));
}
// exact identity: tanh(x) = 1 - 2/(1+e^{2x}); safe at +/-inf (no inf/inf)
__device__ __forceinline__ float tanh_f(float x) {
    return 1.f - 2.f / (1.f + __expf(2.f * x));
}

__global__ void convert_kernel(const float* __restrict__ x, const float* __restrict__ h0,
                               __bf16* __restrict__ xbf, __bf16* __restrict__ hbf,
                               unsigned* __restrict__ bar) {
    unsigned idx = blockIdx.x * 256u + threadIdx.x;
    if (idx == 0) { bar[0] = 0u; bar[16] = 0u; }
    if (idx < 16384u) {  // h0: 65536 floats = 16384 float4
        f32x4 v = ((const f32x4*)h0)[idx];
        bf16x4 o; o[0]=(__bf16)v[0]; o[1]=(__bf16)v[1]; o[2]=(__bf16)v[2]; o[3]=(__bf16)v[3];
        ((bf16x4*)hbf)[idx] = o;
    }
    // x: 33554432 floats = 8388608 float4; grid sized exactly
    f32x4 v = ((const f32x4*)x)[idx];
    bf16x4 o; o[0]=(__bf16)v[0]; o[1]=(__bf16)v[1]; o[2]=(__bf16)v[2]; o[3]=(__bf16)v[3];
    ((bf16x4*)xbf)[idx] = o;
}

__global__ __launch_bounds__(256, 1) void lstm_kernel(
    const float* __restrict__ c0,
    const float* __restrict__ W_ih, const float* __restrict__ W_hh,
    const float* __restrict__ b_ih, const float* __restrict__ b_hh,
    const __bf16* __restrict__ xbf,      // [512][64][1024] bf16
    __bf16* __restrict__ hbuf,           // [2][64][1024] bf16 double buffer
    unsigned* bar,
    float* __restrict__ out)             // d_out: y[65536], h[65536], c[65536]
{
    const int tid  = threadIdx.x;
    const int lane = tid & 63;
    const int w    = tid >> 6;           // wave id: K-quarter
    const int quad = lane >> 4;
    const int l15  = lane & 15;
    const int hbase = blockIdx.x * 8;    // first hidden unit owned by this WG

    // cross-wave reduction buffer: [wave][batch col][row padded 32->44]
    __shared__ float red[4][64][44];     // 45056 B

    // ---- weight preload into registers (once). Block row n = gate*8 + unit.
    // A-frag (16x16x32 bf16): lane holds A[m = l&15][k = quad*8 + j], j=0..7.
    bf16x8 wf[2][16];
    #pragma unroll
    for (int mt = 0; mt < 2; ++mt) {
        const int n    = mt * 16 + l15;
        const int grow = (n >> 3) * HID + hbase + (n & 7);   // global weight row
        #pragma unroll
        for (int kk = 0; kk < 16; ++kk) {
            const int kglob = w * 512 + kk * 32 + quad * 8;  // wave-uniform branch below
            const float* src = (kglob < 1024)
                ? (W_ih + (size_t)grow * 1024 + kglob)
                : (W_hh + (size_t)grow * 1024 + (kglob - 1024));
            f32x4 a = *(const f32x4*)src;
            f32x4 b = *(const f32x4*)(src + 4);
            bf16x8 f;
            f[0]=(__bf16)a[0]; f[1]=(__bf16)a[1]; f[2]=(__bf16)a[2]; f[3]=(__bf16)a[3];
            f[4]=(__bf16)b[0]; f[5]=(__bf16)b[1]; f[6]=(__bf16)b[2]; f[7]=(__bf16)b[3];
            wf[mt][kk] = f;
        }
    }

    // per-thread cell state: pairs (cb,cu) and (cb,cu+1); cu even
    const int p0 = tid * 2;
    const int cb = p0 >> 3;
    const int cu = p0 & 7;
    float c0v = c0[cb * HID + hbase + cu];
    float c1v = c0[cb * HID + hbase + cu + 1];

    // bias preload (loop-invariant)
    float bias0[4], bias1[4];
    #pragma unroll
    for (int gate = 0; gate < 4; ++gate) {
        int gr = gate * HID + hbase + cu;
        bias0[gate] = b_ih[gr] + b_hh[gr];
        bias1[gate] = b_ih[gr + 1] + b_hh[gr + 1];
    }

    const bool isx = (w < 2);
    const int  kb  = (w & 1) * 512;

    for (int t = 0; t < L_STEPS; ++t) {
        const __bf16* act = isx ? (xbf + (size_t)t * (NB * HID) + kb)
                                : (hbuf + (size_t)(t & 1) * (NB * HID) + kb);

        f32x4 acc[2][4];
        #pragma unroll
        for (int mt = 0; mt < 2; ++mt)
            #pragma unroll
            for (int nt = 0; nt < 4; ++nt) {
                f32x4 z = {0.f, 0.f, 0.f, 0.f};
                acc[mt][nt] = z;
            }

        #pragma unroll
        for (int kk = 0; kk < 16; ++kk) {
            bf16x8 bfr[4];
            #pragma unroll
            for (int nt = 0; nt < 4; ++nt) {
                const int brow = nt * 16 + l15;   // batch row (B-frag n = l&15)
                bfr[nt] = *(const bf16x8*)(act + (size_t)brow * HID + kk * 32 + quad * 8);
            }
            #pragma unroll
            for (int mt = 0; mt < 2; ++mt)
                #pragma unroll
                for (int nt = 0; nt < 4; ++nt)
                    acc[mt][nt] = __builtin_amdgcn_mfma_f32_16x16x32_bf16(
                        wf[mt][kk], bfr[nt], acc[mt][nt], 0, 0, 0);
        }

        // partials -> LDS.  C/D layout: col = lane&15 (batch), row = quad*4+reg.
        #pragma unroll
        for (int mt = 0; mt < 2; ++mt)
            #pragma unroll
            for (int nt = 0; nt < 4; ++nt) {
                const int row0 = mt * 16 + quad * 4;
                const int col  = nt * 16 + l15;
                *(f32x4*)&red[w][col][row0] = acc[mt][nt];
            }
        __syncthreads();

        // gate phase: sum 4 wave partials, add bias, LSTM update
        float h0v, h1v;
        {
            float z0[4], z1[4];
            #pragma unroll
            for (int gate = 0; gate < 4; ++gate) {
                const int row = gate * 8 + cu;
                f32x2 s0 = *(const f32x2*)&red[0][cb][row];
                f32x2 s1 = *(const f32x2*)&red[1][cb][row];
                f32x2 s2 = *(const f32x2*)&red[2][cb][row];
                f32x2 s3 = *(const f32x2*)&red[3][cb][row];
                z0[gate] = s0[0] + s1[0] + s2[0] + s3[0] + bias0[gate];
                z1[gate] = s0[1] + s1[1] + s2[1] + s3[1] + bias1[gate];
            }
            float ig = sigmoid_f(z0[0]), fg = sigmoid_f(z0[1]);
            float gg = tanh_f(z0[2]),    og = sigmoid_f(z0[3]);
            c0v = fg * c0v + ig * gg;
            h0v = og * tanh_f(c0v);
            ig = sigmoid_f(z1[0]); fg = sigmoid_f(z1[1]);
            gg = tanh_f(z1[2]);    og = sigmoid_f(z1[3]);
            c1v = fg * c1v + ig * gg;
            h1v = og * tanh_f(c1v);
        }
        {
            bf16x2 hv; hv[0] = (__bf16)h0v; hv[1] = (__bf16)h1v;
            __bf16* dst = hbuf + (size_t)((t + 1) & 1) * (NB * HID) + cb * HID + hbase + cu;
            *(bf16x2*)dst = hv;
        }
        if (t == L_STEPS - 1) {
            const int idx = cb * HID + hbase + cu;
            out[65536 + idx]      = h0v;
            out[65536 + idx + 1]  = h1v;
            out[131072 + idx]     = c0v;
            out[131072 + idx + 1] = c1v;
        }

        // ---- device-scope grid barrier (sense via generation counter) ----
        __syncthreads();
        if (tid == 0) {
            __threadfence();
            unsigned prev = __hip_atomic_fetch_add(&bar[0], 1u, __ATOMIC_ACQ_REL,
                                                   __HIP_MEMORY_SCOPE_AGENT);
            if (prev == GRID_LSTM - 1) {
                __hip_atomic_store(&bar[0], 0u, __ATOMIC_RELAXED, __HIP_MEMORY_SCOPE_AGENT);
                __hip_atomic_fetch_add(&bar[16], 1u, __ATOMIC_RELEASE, __HIP_MEMORY_SCOPE_AGENT);
            } else {
                while (__hip_atomic_load(&bar[16], __ATOMIC_ACQUIRE,
                                         __HIP_MEMORY_SCOPE_AGENT) < (unsigned)(t + 1)) {
                    __builtin_amdgcn_s_sleep(4);
                }
            }
            __threadfence();
        }
        __syncthreads();
    }
}

__global__ void out_kernel(const float* __restrict__ base, const float* __restrict__ Wout,
                           const float* __restrict__ bout, float* __restrict__ y)
{
    const int wv   = (int)((blockIdx.x * 256u + threadIdx.x) >> 6);  // one wave per output
    const int lane = threadIdx.x & 63;
    const int b = wv >> 10;
    const int i = wv & 1023;
    const f32x4* hp = (const f32x4*)(base + 65536 + b * HID);
    const f32x4* wp = (const f32x4*)(Wout + (size_t)i * HID);
    float acc = 0.f;
    #pragma unroll
    for (int q = 0; q < 4; ++q) {
        f32x4 hv = hp[q * 64 + lane];
        f32x4 wvv = wp[q * 64 + lane];
        acc += hv[0]*wvv[0] + hv[1]*wvv[1] + hv[2]*wvv[2] + hv[3]*wvv[3];
    }
    #pragma unroll
    for (int off = 32; off > 0; off >>= 1) acc += __shfl_down(acc, off);
    if (lane == 0) y[b * HID + i] = acc + bout[i];
}

extern "C" void kernel_launch(void* const* d_in, const int* in_sizes, int n_in,
                              void* d_out, int out_size, void* d_ws, size_t ws_size,
                              hipStream_t stream)
{
    const float* x    = (const float*)d_in[0];
    const float* h0   = (const float*)d_in[1];
    const float* c0   = (const float*)d_in[2];
    const float* W_ih = (const float*)d_in[3];
    const float* W_hh = (const float*)d_in[4];
    const float* b_ih = (const float*)d_in[5];
    const float* b_hh = (const float*)d_in[6];
    const float* Wout = (const float*)d_in[7];
    const float* bout = (const float*)d_in[8];
    float* out = (float*)d_out;

    char* ws = (char*)d_ws;
    __bf16* xbf   = (__bf16*)(ws);                         // 67,108,864 B
    __bf16* hbuf  = (__bf16*)(ws + 67108864);              // 262,144 B
    unsigned* bar = (unsigned*)(ws + 67108864 + 262144);   // 256 B

    convert_kernel<<<32768, 256, 0, stream>>>(x, h0, xbf, hbuf, bar);
    lstm_kernel<<<GRID_LSTM, 256, 0, stream>>>(c0, W_ih, W_hh, b_ih, b_hh,
                                               xbf, hbuf, bar, out);
    out_kernel<<<16384, 256, 0, stream>>>(out, Wout, bout, out);
}

// Round 2
// 6358.722 us; speedup vs baseline: 1.7491x; 1.7491x over previous
//
#include <hip/hip_runtime.h>
#include <hip/hip_bf16.h>

// LSTM: L=512 steps, N=64 batch, I=H=1024.
//  K1: convert x (fp32->bf16) + h0->bf16 + init per-WG barrier flags.
//  K2: persistent fused recurrence. 128 WGs x 256 thr. WG g owns hidden units
//      [8g,8g+8) => 32 rows of combined weights [W_ih|W_hh]. Wave w owns
//      combined-K quarter [256w,256w+256) of BOTH W_ih and W_hh as MFMA
//      A-fragments in 128 VGPRs (loaded once). Per step:
//        poll flags (wave0, RELAXED) -> acquire fence -> sync
//        h-half MFMAs (adds onto x-partials already in acc)
//        LDS reduce -> gate math (c in regs) -> h store (plain, to L2)
//        sync (drains stores to L2) -> tid0: RELEASE fence + flag store
//        x-half MFMAs for t+1 into fresh acc   <- hidden in barrier shadow
//      Exactly 1 release + 1 acquire fence per WG per step.
//  K3: y = h @ W_out^T + b_out, one wave per output element.

#define L_STEPS 512
#define NB 64
#define HID 1024
#define GRID_LSTM 128

typedef __bf16 bf16x8 __attribute__((ext_vector_type(8)));
typedef __bf16 bf16x4 __attribute__((ext_vector_type(4)));
typedef __bf16 bf16x2 __attribute__((ext_vector_type(2)));
typedef float  f32x4  __attribute__((ext_vector_type(4)));
typedef float  f32x2  __attribute__((ext_vector_type(2)));

__device__ __forceinline__ float sigmoid_f(float x) {
    return 1.f / (1.f + __expf(-x));
}
__device__ __forceinline__ float tanh_f(float x) {
    return 1.f - 2.f / (1.f + __expf(2.f * x));
}

__global__ void convert_kernel(const float* __restrict__ x, const float* __restrict__ h0,
                               __bf16* __restrict__ xbf, __bf16* __restrict__ hbf,
                               unsigned* __restrict__ bar) {
    unsigned idx = blockIdx.x * 256u + threadIdx.x;
    if (idx < GRID_LSTM) bar[idx] = 0u;
    if (idx < 16384u) {  // h0: 65536 floats = 16384 float4
        f32x4 v = ((const f32x4*)h0)[idx];
        bf16x4 o; o[0]=(__bf16)v[0]; o[1]=(__bf16)v[1]; o[2]=(__bf16)v[2]; o[3]=(__bf16)v[3];
        ((bf16x4*)hbf)[idx] = o;
    }
    f32x4 v = ((const f32x4*)x)[idx];
    bf16x4 o; o[0]=(__bf16)v[0]; o[1]=(__bf16)v[1]; o[2]=(__bf16)v[2]; o[3]=(__bf16)v[3];
    ((bf16x4*)xbf)[idx] = o;
}

// one MFMA half-phase: 8 K32 slabs against one activation matrix
__device__ __forceinline__ void mfma_half(const __bf16* __restrict__ act,
                                          const bf16x8 (&wfr)[2][8],
                                          int l15, int quad, f32x4 (&acc)[2][4]) {
    #pragma unroll
    for (int kk = 0; kk < 8; ++kk) {
        bf16x8 bfr[4];
        #pragma unroll
        for (int nt = 0; nt < 4; ++nt) {
            const int brow = nt * 16 + l15;
            bfr[nt] = *(const bf16x8*)(act + (size_t)brow * HID + kk * 32 + quad * 8);
        }
        #pragma unroll
        for (int mt = 0; mt < 2; ++mt)
            #pragma unroll
            for (int nt = 0; nt < 4; ++nt)
                acc[mt][nt] = __builtin_amdgcn_mfma_f32_16x16x32_bf16(
                    wfr[mt][kk], bfr[nt], acc[mt][nt], 0, 0, 0);
    }
}

__global__ __launch_bounds__(256, 1) void lstm_kernel(
    const float* __restrict__ c0,
    const float* __restrict__ W_ih, const float* __restrict__ W_hh,
    const float* __restrict__ b_ih, const float* __restrict__ b_hh,
    const __bf16* __restrict__ xbf,      // [512][64][1024] bf16
    __bf16* __restrict__ hbuf,           // [2][64][1024] bf16 double buffer
    unsigned* bar,                       // [128] per-WG step flags
    float* __restrict__ out)             // d_out: y[65536], h[65536], c[65536]
{
    const int tid  = threadIdx.x;
    const int lane = tid & 63;
    const int w    = tid >> 6;           // wave id: combined-K quarter
    const int quad = lane >> 4;
    const int l15  = lane & 15;
    const int hbase = blockIdx.x * 8;

    __shared__ float red[4][64][44];     // [wave][batch][row pad 32->44] = 45056 B

    // ---- weight preload (once). wave w covers cols [256w, 256w+256) of both
    // W_ih (x half) and W_hh (h half). A-frag: lane = A[m=l15][k=quad*8+j].
    bf16x8 wfx[2][8], wfh[2][8];
    #pragma unroll
    for (int mt = 0; mt < 2; ++mt) {
        const int n    = mt * 16 + l15;
        const int grow = (n >> 3) * HID + hbase + (n & 7);
        #pragma unroll
        for (int kk = 0; kk < 8; ++kk) {
            const int kcol = w * 256 + kk * 32 + quad * 8;
            {
                const float* src = W_ih + (size_t)grow * 1024 + kcol;
                f32x4 a = *(const f32x4*)src;
                f32x4 b = *(const f32x4*)(src + 4);
                bf16x8 f;
                f[0]=(__bf16)a[0]; f[1]=(__bf16)a[1]; f[2]=(__bf16)a[2]; f[3]=(__bf16)a[3];
                f[4]=(__bf16)b[0]; f[5]=(__bf16)b[1]; f[6]=(__bf16)b[2]; f[7]=(__bf16)b[3];
                wfx[mt][kk] = f;
            }
            {
                const float* src = W_hh + (size_t)grow * 1024 + kcol;
                f32x4 a = *(const f32x4*)src;
                f32x4 b = *(const f32x4*)(src + 4);
                bf16x8 f;
                f[0]=(__bf16)a[0]; f[1]=(__bf16)a[1]; f[2]=(__bf16)a[2]; f[3]=(__bf16)a[3];
                f[4]=(__bf16)b[0]; f[5]=(__bf16)b[1]; f[6]=(__bf16)b[2]; f[7]=(__bf16)b[3];
                wfh[mt][kk] = f;
            }
        }
    }

    // per-thread cell state: pairs (cb, cu) and (cb, cu+1)
    const int p0 = tid * 2;
    const int cb = p0 >> 3;
    const int cu = p0 & 7;
    float c0v = c0[cb * HID + hbase + cu];
    float c1v = c0[cb * HID + hbase + cu + 1];

    float bias0[4], bias1[4];
    #pragma unroll
    for (int gate = 0; gate < 4; ++gate) {
        int gr = gate * HID + hbase + cu;
        bias0[gate] = b_ih[gr] + b_hh[gr];
        bias1[gate] = b_ih[gr + 1] + b_hh[gr + 1];
    }

    // prologue: x-partials for t=0
    f32x4 acc[2][4];
    #pragma unroll
    for (int mt = 0; mt < 2; ++mt)
        #pragma unroll
        for (int nt = 0; nt < 4; ++nt) { f32x4 z = {0.f,0.f,0.f,0.f}; acc[mt][nt] = z; }
    mfma_half(xbf + (size_t)0 + w * 256, wfx, l15, quad, acc);

    for (int t = 0; t < L_STEPS; ++t) {
        // ---- wait for h_t: wave 0 polls per-WG flags (RELAXED, no cache ops)
        if (w == 0) {
            for (;;) {
                unsigned f0 = __hip_atomic_load(&bar[lane], __ATOMIC_RELAXED,
                                                __HIP_MEMORY_SCOPE_AGENT);
                unsigned f1 = __hip_atomic_load(&bar[64 + lane], __ATOMIC_RELAXED,
                                                __HIP_MEMORY_SCOPE_AGENT);
                if (__all((f0 >= (unsigned)t) && (f1 >= (unsigned)t))) break;
                __builtin_amdgcn_s_sleep(1);
            }
            __builtin_amdgcn_fence(__ATOMIC_ACQUIRE, "agent");  // one inv per step
        }
        __syncthreads();

        // ---- h half: accumulate onto x-partials already in acc
        mfma_half(hbuf + (size_t)(t & 1) * (NB * HID) + w * 256, wfh, l15, quad, acc);

        // partials -> LDS. C/D layout: col = lane&15 (batch), row = quad*4+reg.
        #pragma unroll
        for (int mt = 0; mt < 2; ++mt)
            #pragma unroll
            for (int nt = 0; nt < 4; ++nt) {
                const int row0 = mt * 16 + quad * 4;
                const int col  = nt * 16 + l15;
                *(f32x4*)&red[w][col][row0] = acc[mt][nt];
            }
        __syncthreads();

        // ---- gate phase
        float h0v, h1v;
        {
            float z0[4], z1[4];
            #pragma unroll
            for (int gate = 0; gate < 4; ++gate) {
                const int row = gate * 8 + cu;
                f32x2 s0 = *(const f32x2*)&red[0][cb][row];
                f32x2 s1 = *(const f32x2*)&red[1][cb][row];
                f32x2 s2 = *(const f32x2*)&red[2][cb][row];
                f32x2 s3 = *(const f32x2*)&red[3][cb][row];
                z0[gate] = s0[0] + s1[0] + s2[0] + s3[0] + bias0[gate];
                z1[gate] = s0[1] + s1[1] + s2[1] + s3[1] + bias1[gate];
            }
            float ig = sigmoid_f(z0[0]), fg = sigmoid_f(z0[1]);
            float gg = tanh_f(z0[2]),    og = sigmoid_f(z0[3]);
            c0v = fg * c0v + ig * gg;
            h0v = og * tanh_f(c0v);
            ig = sigmoid_f(z1[0]); fg = sigmoid_f(z1[1]);
            gg = tanh_f(z1[2]);    og = sigmoid_f(z1[3]);
            c1v = fg * c1v + ig * gg;
            h1v = og * tanh_f(c1v);
        }
        {
            bf16x2 hv; hv[0] = (__bf16)h0v; hv[1] = (__bf16)h1v;
            __bf16* dst = hbuf + (size_t)((t + 1) & 1) * (NB * HID) + cb * HID + hbase + cu;
            *(bf16x2*)dst = hv;
        }
        if (t == L_STEPS - 1) {
            const int idx = cb * HID + hbase + cu;
            out[65536 + idx]      = h0v;
            out[65536 + idx + 1]  = h1v;
            out[131072 + idx]     = c0v;
            out[131072 + idx + 1] = c1v;
        }

        // ---- publish h_{t+1}: drain all waves' stores to L2, then one
        // release fence (wbl2) + per-WG flag store.
        __syncthreads();
        if (tid == 0) {
            __builtin_amdgcn_fence(__ATOMIC_RELEASE, "agent");
            __hip_atomic_store(&bar[blockIdx.x], (unsigned)(t + 1), __ATOMIC_RELAXED,
                               __HIP_MEMORY_SCOPE_AGENT);
        }

        // ---- x half for t+1 (hidden in other WGs' arrival shadow)
        #pragma unroll
        for (int mt = 0; mt < 2; ++mt)
            #pragma unroll
            for (int nt = 0; nt < 4; ++nt) { f32x4 z = {0.f,0.f,0.f,0.f}; acc[mt][nt] = z; }
        if (t < L_STEPS - 1)
            mfma_half(xbf + (size_t)(t + 1) * (NB * HID) + w * 256, wfx, l15, quad, acc);
    }
}

__global__ void out_kernel(const float* __restrict__ base, const float* __restrict__ Wout,
                           const float* __restrict__ bout, float* __restrict__ y)
{
    const int wv   = (int)((blockIdx.x * 256u + threadIdx.x) >> 6);
    const int lane = threadIdx.x & 63;
    const int b = wv >> 10;
    const int i = wv & 1023;
    const f32x4* hp = (const f32x4*)(base + 65536 + b * HID);
    const f32x4* wp = (const f32x4*)(Wout + (size_t)i * HID);
    float acc = 0.f;
    #pragma unroll
    for (int q = 0; q < 4; ++q) {
        f32x4 hv = hp[q * 64 + lane];
        f32x4 wvv = wp[q * 64 + lane];
        acc += hv[0]*wvv[0] + hv[1]*wvv[1] + hv[2]*wvv[2] + hv[3]*wvv[3];
    }
    #pragma unroll
    for (int off = 32; off > 0; off >>= 1) acc += __shfl_down(acc, off);
    if (lane == 0) y[b * HID + i] = acc + bout[i];
}

extern "C" void kernel_launch(void* const* d_in, const int* in_sizes, int n_in,
                              void* d_out, int out_size, void* d_ws, size_t ws_size,
                              hipStream_t stream)
{
    const float* x    = (const float*)d_in[0];
    const float* h0   = (const float*)d_in[1];
    const float* c0   = (const float*)d_in[2];
    const float* W_ih = (const float*)d_in[3];
    const float* W_hh = (const float*)d_in[4];
    const float* b_ih = (const float*)d_in[5];
    const float* b_hh = (const float*)d_in[6];
    const float* Wout = (const float*)d_in[7];
    const float* bout = (const float*)d_in[8];
    float* out = (float*)d_out;

    char* ws = (char*)d_ws;
    __bf16* xbf   = (__bf16*)(ws);                         // 67,108,864 B
    __bf16* hbuf  = (__bf16*)(ws + 67108864);              // 262,144 B
    unsigned* bar = (unsigned*)(ws + 67108864 + 262144);   // 512 B

    convert_kernel<<<32768, 256, 0, stream>>>(x, h0, xbf, hbuf, bar);
    lstm_kernel<<<GRID_LSTM, 256, 0, stream>>>(c0, W_ih, W_hh, b_ih, b_hh,
                                               xbf, hbuf, bar, out);
    out_kernel<<<16384, 256, 0, stream>>>(out, Wout, bout, out);
}

// Round 3
// 5196.541 us; speedup vs baseline: 2.1403x; 1.2236x over previous
//
#include <hip/hip_runtime.h>
#include <hip/hip_bf16.h>

// LSTM: L=512 steps, N=64 batch, I=H=1024.
//  K1: convert x (fp32->bf16) + h0->bf16 + init per-wave barrier flags.
//  K2: persistent fused recurrence. 128 WGs x 256 thr. WG g owns hidden units
//      [8g,8g+8). Wave w owns combined-K quarter [256w,256w+256) of W_ih and
//      W_hh as MFMA A-fragments in 128 VGPRs (loaded once).
//      h moves cross-XCD through the coherence point with sc1 loads/stores
//      (same mechanism LLVM uses for agent-scope atomics) -> ZERO wbl2/inv
//      fences in the step loop. Per-wave flags: wave w polls only its 32
//      producer WGs (x4 waves); WG-internal syncthreads preserves the
//      double-buffer overwrite safety (union of 4 waves' polls = whole grid).
//  K3: y = h @ W_out^T + b_out, one wave per output element.

#define L_STEPS 512
#define NB 64
#define HID 1024
#define GRID_LSTM 128

typedef __bf16 bf16x8 __attribute__((ext_vector_type(8)));
typedef __bf16 bf16x4 __attribute__((ext_vector_type(4)));
typedef __bf16 bf16x2 __attribute__((ext_vector_type(2)));
typedef float  f32x4  __attribute__((ext_vector_type(4)));
typedef float  f32x2  __attribute__((ext_vector_type(2)));
typedef unsigned u32x4 __attribute__((ext_vector_type(4)));

__device__ __forceinline__ float sigmoid_f(float x) {
    return 1.f / (1.f + __expf(-x));
}
__device__ __forceinline__ float tanh_f(float x) {
    return 1.f - 2.f / (1.f + __expf(2.f * x));
}

__global__ void convert_kernel(const float* __restrict__ x, const float* __restrict__ h0,
                               __bf16* __restrict__ xbf, __bf16* __restrict__ hbf,
                               unsigned* __restrict__ bar) {
    unsigned idx = blockIdx.x * 256u + threadIdx.x;
    if (idx < 512u) bar[idx] = 0u;     // 128 WGs x 4 waves
    if (idx < 16384u) {                // h0: 65536 floats = 16384 float4
        f32x4 v = ((const f32x4*)h0)[idx];
        bf16x4 o; o[0]=(__bf16)v[0]; o[1]=(__bf16)v[1]; o[2]=(__bf16)v[2]; o[3]=(__bf16)v[3];
        ((bf16x4*)hbf)[idx] = o;
    }
    f32x4 v = ((const f32x4*)x)[idx];
    bf16x4 o; o[0]=(__bf16)v[0]; o[1]=(__bf16)v[1]; o[2]=(__bf16)v[2]; o[3]=(__bf16)v[3];
    ((bf16x4*)xbf)[idx] = o;
}

// x half-phase: plain (L2-cached) loads, 8 K32 slabs
__device__ __forceinline__ void mfma_x(const __bf16* __restrict__ act,
                                       const bf16x8 (&wfr)[2][8],
                                       int l15, int quad, f32x4 (&acc)[2][4]) {
    #pragma unroll
    for (int kk = 0; kk < 8; ++kk) {
        bf16x8 bfr[4];
        #pragma unroll
        for (int nt = 0; nt < 4; ++nt) {
            const int brow = nt * 16 + l15;
            bfr[nt] = *(const bf16x8*)(act + (size_t)brow * HID + kk * 32 + quad * 8);
        }
        #pragma unroll
        for (int mt = 0; mt < 2; ++mt)
            #pragma unroll
            for (int nt = 0; nt < 4; ++nt)
                acc[mt][nt] = __builtin_amdgcn_mfma_f32_16x16x32_bf16(
                    wfr[mt][kk], bfr[nt], acc[mt][nt], 0, 0, 0);
    }
}

__global__ __launch_bounds__(256, 1) void lstm_kernel(
    const float* __restrict__ c0,
    const float* __restrict__ W_ih, const float* __restrict__ W_hh,
    const float* __restrict__ b_ih, const float* __restrict__ b_hh,
    const __bf16* __restrict__ xbf,      // [512][64][1024] bf16
    __bf16* hbuf,                        // [2][64][1024] bf16 double buffer
    unsigned* bar,                       // [512] per-wave step flags (wg*4+w)
    float* __restrict__ out)             // d_out: y[65536], h[65536], c[65536]
{
    const int tid  = threadIdx.x;
    const int lane = tid & 63;
    const int w    = tid >> 6;           // wave id: combined-K quarter
    const int quad = lane >> 4;
    const int l15  = lane & 15;
    const int hbase = blockIdx.x * 8;

    __shared__ float red[4][64][44];     // [wave][batch][row pad 32->44] = 45056 B

    // ---- weight preload (once). A-frag: lane = A[m=l15][k=quad*8+j].
    bf16x8 wfx[2][8], wfh[2][8];
    #pragma unroll
    for (int mt = 0; mt < 2; ++mt) {
        const int n    = mt * 16 + l15;
        const int grow = (n >> 3) * HID + hbase + (n & 7);
        #pragma unroll
        for (int kk = 0; kk < 8; ++kk) {
            const int kcol = w * 256 + kk * 32 + quad * 8;
            {
                const float* src = W_ih + (size_t)grow * 1024 + kcol;
                f32x4 a = *(const f32x4*)src;
                f32x4 b = *(const f32x4*)(src + 4);
                bf16x8 f;
                f[0]=(__bf16)a[0]; f[1]=(__bf16)a[1]; f[2]=(__bf16)a[2]; f[3]=(__bf16)a[3];
                f[4]=(__bf16)b[0]; f[5]=(__bf16)b[1]; f[6]=(__bf16)b[2]; f[7]=(__bf16)b[3];
                wfx[mt][kk] = f;
            }
            {
                const float* src = W_hh + (size_t)grow * 1024 + kcol;
                f32x4 a = *(const f32x4*)src;
                f32x4 b = *(const f32x4*)(src + 4);
                bf16x8 f;
                f[0]=(__bf16)a[0]; f[1]=(__bf16)a[1]; f[2]=(__bf16)a[2]; f[3]=(__bf16)a[3];
                f[4]=(__bf16)b[0]; f[5]=(__bf16)b[1]; f[6]=(__bf16)b[2]; f[7]=(__bf16)b[3];
                wfh[mt][kk] = f;
            }
        }
    }

    // per-thread cell state: pairs (cb, cu) and (cb, cu+1)
    const int p0 = tid * 2;
    const int cb = p0 >> 3;              // batch row; wave v covers cb in [16v,16v+16)
    const int cu = p0 & 7;
    float c0v = c0[cb * HID + hbase + cu];
    float c1v = c0[cb * HID + hbase + cu + 1];

    float bias0[4], bias1[4];
    #pragma unroll
    for (int gate = 0; gate < 4; ++gate) {
        int gr = gate * HID + hbase + cu;
        bias0[gate] = b_ih[gr] + b_hh[gr];
        bias1[gate] = b_ih[gr + 1] + b_hh[gr + 1];
    }

    // prologue: x-partials for t=0
    f32x4 acc[2][4];
    #pragma unroll
    for (int mt = 0; mt < 2; ++mt)
        #pragma unroll
        for (int nt = 0; nt < 4; ++nt) { f32x4 z = {0.f,0.f,0.f,0.f}; acc[mt][nt] = z; }
    mfma_x(xbf + (size_t)0 + w * 256, wfx, l15, quad, acc);

    // my producer set: WGs [32w, 32w+32), all 4 waves each => flags [128w, 128w+128)
    const int pf0 = 128 * w + lane;
    const int pf1 = 128 * w + 64 + lane;

    for (int t = 0; t < L_STEPS; ++t) {
        // ---- per-wave wait for h_t producers (relaxed sc1 polls, no fences)
        for (;;) {
            unsigned f0 = __hip_atomic_load(&bar[pf0], __ATOMIC_RELAXED,
                                            __HIP_MEMORY_SCOPE_AGENT);
            unsigned f1 = __hip_atomic_load(&bar[pf1], __ATOMIC_RELAXED,
                                            __HIP_MEMORY_SCOPE_AGENT);
            if (__all((f0 >= (unsigned)t) && (f1 >= (unsigned)t))) break;
            __builtin_amdgcn_s_sleep(1);
        }

        // ---- h half: 32 sc1 loads straight from the coherence point
        u32x4 hb[8][4];
        const __bf16* hb_base = hbuf + (size_t)(t & 1) * (NB * HID) + w * 256 + quad * 8;
        #pragma unroll
        for (int kk = 0; kk < 8; ++kk)
            #pragma unroll
            for (int nt = 0; nt < 4; ++nt) {
                const __bf16* p = hb_base + (size_t)(nt * 16 + l15) * HID + kk * 32;
                asm volatile("global_load_dwordx4 %0, %1, off sc1"
                             : "=v"(hb[kk][nt]) : "v"(p));
            }
        asm volatile("s_waitcnt vmcnt(0)"
            : "+v"(hb[0][0]), "+v"(hb[0][1]), "+v"(hb[0][2]), "+v"(hb[0][3]),
              "+v"(hb[1][0]), "+v"(hb[1][1]), "+v"(hb[1][2]), "+v"(hb[1][3]),
              "+v"(hb[2][0]), "+v"(hb[2][1]), "+v"(hb[2][2]), "+v"(hb[2][3]),
              "+v"(hb[3][0]), "+v"(hb[3][1]), "+v"(hb[3][2]), "+v"(hb[3][3]));
        #pragma unroll
        for (int kk = 0; kk < 8; ++kk)
            #pragma unroll
            for (int mt = 0; mt < 2; ++mt)
                #pragma unroll
                for (int nt = 0; nt < 4; ++nt)
                    acc[mt][nt] = __builtin_amdgcn_mfma_f32_16x16x32_bf16(
                        wfh[mt][kk], __builtin_bit_cast(bf16x8, hb[kk][nt]),
                        acc[mt][nt], 0, 0, 0);

        // ---- WAR barrier: prior step's gate reads done before red overwrite
        __syncthreads();

        // partials -> LDS. C/D layout: col = lane&15 (batch), row = quad*4+reg.
        #pragma unroll
        for (int mt = 0; mt < 2; ++mt)
            #pragma unroll
            for (int nt = 0; nt < 4; ++nt) {
                const int row0 = mt * 16 + quad * 4;
                const int col  = nt * 16 + l15;
                *(f32x4*)&red[w][col][row0] = acc[mt][nt];
            }
        __syncthreads();

        // ---- gate phase
        float h0v, h1v;
        {
            float z0[4], z1[4];
            #pragma unroll
            for (int gate = 0; gate < 4; ++gate) {
                const int row = gate * 8 + cu;
                f32x2 s0 = *(const f32x2*)&red[0][cb][row];
                f32x2 s1 = *(const f32x2*)&red[1][cb][row];
                f32x2 s2 = *(const f32x2*)&red[2][cb][row];
                f32x2 s3 = *(const f32x2*)&red[3][cb][row];
                z0[gate] = s0[0] + s1[0] + s2[0] + s3[0] + bias0[gate];
                z1[gate] = s0[1] + s1[1] + s2[1] + s3[1] + bias1[gate];
            }
            float ig = sigmoid_f(z0[0]), fg = sigmoid_f(z0[1]);
            float gg = tanh_f(z0[2]),    og = sigmoid_f(z0[3]);
            c0v = fg * c0v + ig * gg;
            h0v = og * tanh_f(c0v);
            ig = sigmoid_f(z1[0]); fg = sigmoid_f(z1[1]);
            gg = tanh_f(z1[2]);    og = sigmoid_f(z1[3]);
            c1v = fg * c1v + ig * gg;
            h1v = og * tanh_f(c1v);
        }

        // ---- publish h_{t+1}: sc1 store to coherence point, wave-level drain,
        // per-wave flag. No fences, no WG barrier on this path.
        {
            bf16x2 hv; hv[0] = (__bf16)h0v; hv[1] = (__bf16)h1v;
            unsigned hbits = __builtin_bit_cast(unsigned, hv);
            const __bf16* dst = hbuf + (size_t)((t + 1) & 1) * (NB * HID)
                                + cb * HID + hbase + cu;
            asm volatile("global_store_dword %0, %1, off sc1"
                         :: "v"(dst), "v"(hbits) : "memory");
        }
        if (t == L_STEPS - 1) {
            const int idx = cb * HID + hbase + cu;
            out[65536 + idx]      = h0v;
            out[65536 + idx + 1]  = h1v;
            out[131072 + idx]     = c0v;
            out[131072 + idx + 1] = c1v;
        }
        asm volatile("s_waitcnt vmcnt(0)" ::: "memory");
        if (lane == 0)
            __hip_atomic_store(&bar[blockIdx.x * 4 + w], (unsigned)(t + 1),
                               __ATOMIC_RELAXED, __HIP_MEMORY_SCOPE_AGENT);

        // ---- x half for t+1 (off the inter-WG critical path)
        #pragma unroll
        for (int mt = 0; mt < 2; ++mt)
            #pragma unroll
            for (int nt = 0; nt < 4; ++nt) { f32x4 z = {0.f,0.f,0.f,0.f}; acc[mt][nt] = z; }
        if (t < L_STEPS - 1)
            mfma_x(xbf + (size_t)(t + 1) * (NB * HID) + w * 256, wfx, l15, quad, acc);
    }
}

__global__ void out_kernel(const float* __restrict__ base, const float* __restrict__ Wout,
                           const float* __restrict__ bout, float* __restrict__ y)
{
    const int wv   = (int)((blockIdx.x * 256u + threadIdx.x) >> 6);
    const int lane = threadIdx.x & 63;
    const int b = wv >> 10;
    const int i = wv & 1023;
    const f32x4* hp = (const f32x4*)(base + 65536 + b * HID);
    const f32x4* wp = (const f32x4*)(Wout + (size_t)i * HID);
    float acc = 0.f;
    #pragma unroll
    for (int q = 0; q < 4; ++q) {
        f32x4 hv = hp[q * 64 + lane];
        f32x4 wvv = wp[q * 64 + lane];
        acc += hv[0]*wvv[0] + hv[1]*wvv[1] + hv[2]*wvv[2] + hv[3]*wvv[3];
    }
    #pragma unroll
    for (int off = 32; off > 0; off >>= 1) acc += __shfl_down(acc, off);
    if (lane == 0) y[b * HID + i] = acc + bout[i];
}

extern "C" void kernel_launch(void* const* d_in, const int* in_sizes, int n_in,
                              void* d_out, int out_size, void* d_ws, size_t ws_size,
                              hipStream_t stream)
{
    const float* x    = (const float*)d_in[0];
    const float* h0   = (const float*)d_in[1];
    const float* c0   = (const float*)d_in[2];
    const float* W_ih = (const float*)d_in[3];
    const float* W_hh = (const float*)d_in[4];
    const float* b_ih = (const float*)d_in[5];
    const float* b_hh = (const float*)d_in[6];
    const float* Wout = (const float*)d_in[7];
    const float* bout = (const float*)d_in[8];
    float* out = (float*)d_out;

    char* ws = (char*)d_ws;
    __bf16* xbf   = (__bf16*)(ws);                         // 67,108,864 B
    __bf16* hbuf  = (__bf16*)(ws + 67108864);              // 262,144 B
    unsigned* bar = (unsigned*)(ws + 67108864 + 262144);   // 2,048 B

    convert_kernel<<<32768, 256, 0, stream>>>(x, h0, xbf, hbuf, bar);
    lstm_kernel<<<GRID_LSTM, 256, 0, stream>>>(c0, W_ih, W_hh, b_ih, b_hh,
                                               xbf, hbuf, bar, out);
    out_kernel<<<16384, 256, 0, stream>>>(out, Wout, bout, out);
}

// Round 4
// 3014.049 us; speedup vs baseline: 3.6900x; 1.7241x over previous
//
#include <hip/hip_runtime.h>
#include <hip/hip_bf16.h>

// LSTM: L=512 steps, N=64 batch, I=H=1024.
// Round 4: activations (x, h) stored in PACKED MFMA-B-fragment order so every
// fragment load is 1KB contiguous (full 128B EA granules, 2x EA efficiency vs
// the row-major layout's 64B scatter). Packed layout for a [64 x 1024] slab:
//   element(row, col) -> byte (col>>3)*1024 + row*16 + (col&7)*2
//  K1: convert x fp32->bf16 into packed layout + h0 + flag init.
//  K2: persistent recurrence, 128 WGs x 256 thr (as r3): register-resident
//      weights (128 VGPR/wave), per-wave producer-subset flag polling, sc1
//      h exchange through the coherence point, zero cache-maintenance fences.
//      h-load wait split in 2 groups to overlap EA streaming with MFMA.
//  K3: y = h @ W_out^T + b_out.

#define L_STEPS 512
#define NB 64
#define HID 1024
#define GRID_LSTM 128

typedef __bf16 bf16x8 __attribute__((ext_vector_type(8)));
typedef __bf16 bf16x4 __attribute__((ext_vector_type(4)));
typedef __bf16 bf16x2 __attribute__((ext_vector_type(2)));
typedef float  f32x4  __attribute__((ext_vector_type(4)));
typedef float  f32x2  __attribute__((ext_vector_type(2)));
typedef unsigned u32x4 __attribute__((ext_vector_type(4)));

__device__ __forceinline__ float sigmoid_f(float x) {
    return 1.f / (1.f + __expf(-x));
}
__device__ __forceinline__ float tanh_f(float x) {
    return 1.f - 2.f / (1.f + __expf(2.f * x));
}

// Thread u handles one packed 16B unit: row = u&63, cg = (u>>6)&127, t = u>>13.
// Packed store index == u (by construction), so stores are fully coalesced.
__global__ void convert_kernel(const float* __restrict__ x, const float* __restrict__ h0,
                               __bf16* __restrict__ xbf, __bf16* __restrict__ hbf,
                               unsigned* __restrict__ bar) {
    unsigned u = blockIdx.x * 256u + threadIdx.x;
    if (u < 512u) bar[u] = 0u;
    const int row = u & 63;
    const int cg  = (u >> 6) & 127;
    if (u < 8192u) {   // h0 -> packed parity-0 buffer
        const float* s = h0 + (size_t)row * HID + cg * 8;
        f32x4 a = *(const f32x4*)s, b = *(const f32x4*)(s + 4);
        bf16x8 o;
        o[0]=(__bf16)a[0]; o[1]=(__bf16)a[1]; o[2]=(__bf16)a[2]; o[3]=(__bf16)a[3];
        o[4]=(__bf16)b[0]; o[5]=(__bf16)b[1]; o[6]=(__bf16)b[2]; o[7]=(__bf16)b[3];
        ((bf16x8*)hbf)[u] = o;
    }
    const int t = u >> 13;
    const float* s = x + ((size_t)t * NB + row) * HID + cg * 8;
    f32x4 a = *(const f32x4*)s, b = *(const f32x4*)(s + 4);
    bf16x8 o;
    o[0]=(__bf16)a[0]; o[1]=(__bf16)a[1]; o[2]=(__bf16)a[2]; o[3]=(__bf16)a[3];
    o[4]=(__bf16)b[0]; o[5]=(__bf16)b[1]; o[6]=(__bf16)b[2]; o[7]=(__bf16)b[3];
    ((bf16x8*)xbf)[u] = o;
}

// x half-phase on a packed slab. act = slab_base + per-lane offset
// (32w+quad)*512 + l15*8 (elements). Frag (kk,nt) = act + kk*2048 + nt*128.
__device__ __forceinline__ void mfma_x(const __bf16* __restrict__ act,
                                       const bf16x8 (&wfr)[2][8],
                                       f32x4 (&acc)[2][4]) {
    #pragma unroll
    for (int kk = 0; kk < 8; ++kk) {
        bf16x8 bfr[4];
        #pragma unroll
        for (int nt = 0; nt < 4; ++nt)
            bfr[nt] = *(const bf16x8*)(act + kk * 2048 + nt * 128);
        #pragma unroll
        for (int mt = 0; mt < 2; ++mt)
            #pragma unroll
            for (int nt = 0; nt < 4; ++nt)
                acc[mt][nt] = __builtin_amdgcn_mfma_f32_16x16x32_bf16(
                    wfr[mt][kk], bfr[nt], acc[mt][nt], 0, 0, 0);
    }
}

__global__ __launch_bounds__(256, 1) void lstm_kernel(
    const float* __restrict__ c0,
    const float* __restrict__ W_ih, const float* __restrict__ W_hh,
    const float* __restrict__ b_ih, const float* __restrict__ b_hh,
    const __bf16* __restrict__ xbf,      // [512] packed 64x1024 slabs
    __bf16* hbuf,                        // [2] packed 64x1024 slabs
    unsigned* bar,                       // [512] per-wave step flags (wg*4+w)
    float* __restrict__ out)             // d_out: y[65536], h[65536], c[65536]
{
    const int tid  = threadIdx.x;
    const int lane = tid & 63;
    const int w    = tid >> 6;           // wave id: combined-K quarter
    const int quad = lane >> 4;
    const int l15  = lane & 15;
    const int hbase = blockIdx.x * 8;

    __shared__ float red[4][64][44];     // [wave][batch][row pad 32->44] = 45056 B

    // ---- weight preload (once, from row-major fp32 W).
    bf16x8 wfx[2][8], wfh[2][8];
    #pragma unroll
    for (int mt = 0; mt < 2; ++mt) {
        const int n    = mt * 16 + l15;
        const int grow = (n >> 3) * HID + hbase + (n & 7);
        #pragma unroll
        for (int kk = 0; kk < 8; ++kk) {
            const int kcol = w * 256 + kk * 32 + quad * 8;
            {
                const float* src = W_ih + (size_t)grow * 1024 + kcol;
                f32x4 a = *(const f32x4*)src;
                f32x4 b = *(const f32x4*)(src + 4);
                bf16x8 f;
                f[0]=(__bf16)a[0]; f[1]=(__bf16)a[1]; f[2]=(__bf16)a[2]; f[3]=(__bf16)a[3];
                f[4]=(__bf16)b[0]; f[5]=(__bf16)b[1]; f[6]=(__bf16)b[2]; f[7]=(__bf16)b[3];
                wfx[mt][kk] = f;
            }
            {
                const float* src = W_hh + (size_t)grow * 1024 + kcol;
                f32x4 a = *(const f32x4*)src;
                f32x4 b = *(const f32x4*)(src + 4);
                bf16x8 f;
                f[0]=(__bf16)a[0]; f[1]=(__bf16)a[1]; f[2]=(__bf16)a[2]; f[3]=(__bf16)a[3];
                f[4]=(__bf16)b[0]; f[5]=(__bf16)b[1]; f[6]=(__bf16)b[2]; f[7]=(__bf16)b[3];
                wfh[mt][kk] = f;
            }
        }
    }

    // per-thread cell state: pairs (cb, cu) and (cb, cu+1)
    const int p0 = tid * 2;
    const int cb = p0 >> 3;
    const int cu = p0 & 7;
    float c0v = c0[cb * HID + hbase + cu];
    float c1v = c0[cb * HID + hbase + cu + 1];

    float bias0[4], bias1[4];
    #pragma unroll
    for (int gate = 0; gate < 4; ++gate) {
        int gr = gate * HID + hbase + cu;
        bias0[gate] = b_ih[gr] + b_hh[gr];
        bias1[gate] = b_ih[gr + 1] + b_hh[gr + 1];
    }

    // per-lane packed-slab offset (elements)
    const int lane_off = (32 * w + quad) * 512 + l15 * 8;
    // packed h store offset (elements): cg = blockIdx, row = cb, col&7 = cu
    const int hstore_off = blockIdx.x * 512 + cb * 8 + cu;

    // prologue: x-partials for t=0
    f32x4 acc[2][4];
    #pragma unroll
    for (int mt = 0; mt < 2; ++mt)
        #pragma unroll
        for (int nt = 0; nt < 4; ++nt) { f32x4 z = {0.f,0.f,0.f,0.f}; acc[mt][nt] = z; }
    mfma_x(xbf + lane_off, wfx, acc);

    // producer flag set: WGs [32w, 32w+32) x 4 waves => flags [128w, 128w+128)
    const int pf0 = 128 * w + lane;
    const int pf1 = 128 * w + 64 + lane;

    for (int t = 0; t < L_STEPS; ++t) {
        // ---- per-wave wait for h_t producers (relaxed sc1 polls, no fences)
        for (;;) {
            unsigned f0 = __hip_atomic_load(&bar[pf0], __ATOMIC_RELAXED,
                                            __HIP_MEMORY_SCOPE_AGENT);
            unsigned f1 = __hip_atomic_load(&bar[pf1], __ATOMIC_RELAXED,
                                            __HIP_MEMORY_SCOPE_AGENT);
            if (__all((f0 >= (unsigned)t) && (f1 >= (unsigned)t))) break;
            __builtin_amdgcn_s_sleep(1);
        }

        // ---- h half: 32 sc1 loads, packed layout => 1KB contiguous per instr
        u32x4 hb[8][4];
        const __bf16* hb_base = hbuf + (size_t)(t & 1) * (NB * HID) + lane_off;
        #pragma unroll
        for (int kk = 0; kk < 8; ++kk)
            #pragma unroll
            for (int nt = 0; nt < 4; ++nt) {
                const __bf16* p = hb_base + kk * 2048 + nt * 128;
                asm volatile("global_load_dwordx4 %0, %1, off sc1"
                             : "=v"(hb[kk][nt]) : "v"(p));
            }
        // group 1: wait first 16 loads (kk 0..3), MFMA while rest streams
        asm volatile("s_waitcnt vmcnt(16)"
            : "+v"(hb[0][0]), "+v"(hb[0][1]), "+v"(hb[0][2]), "+v"(hb[0][3]),
              "+v"(hb[1][0]), "+v"(hb[1][1]), "+v"(hb[1][2]), "+v"(hb[1][3]),
              "+v"(hb[2][0]), "+v"(hb[2][1]), "+v"(hb[2][2]), "+v"(hb[2][3]),
              "+v"(hb[3][0]), "+v"(hb[3][1]), "+v"(hb[3][2]), "+v"(hb[3][3]));
        #pragma unroll
        for (int kk = 0; kk < 4; ++kk)
            #pragma unroll
            for (int mt = 0; mt < 2; ++mt)
                #pragma unroll
                for (int nt = 0; nt < 4; ++nt)
                    acc[mt][nt] = __builtin_amdgcn_mfma_f32_16x16x32_bf16(
                        wfh[mt][kk], __builtin_bit_cast(bf16x8, hb[kk][nt]),
                        acc[mt][nt], 0, 0, 0);
        asm volatile("s_waitcnt vmcnt(0)"
            : "+v"(hb[4][0]), "+v"(hb[4][1]), "+v"(hb[4][2]), "+v"(hb[4][3]),
              "+v"(hb[5][0]), "+v"(hb[5][1]), "+v"(hb[5][2]), "+v"(hb[5][3]),
              "+v"(hb[6][0]), "+v"(hb[6][1]), "+v"(hb[6][2]), "+v"(hb[6][3]),
              "+v"(hb[7][0]), "+v"(hb[7][1]), "+v"(hb[7][2]), "+v"(hb[7][3]));
        #pragma unroll
        for (int kk = 4; kk < 8; ++kk)
            #pragma unroll
            for (int mt = 0; mt < 2; ++mt)
                #pragma unroll
                for (int nt = 0; nt < 4; ++nt)
                    acc[mt][nt] = __builtin_amdgcn_mfma_f32_16x16x32_bf16(
                        wfh[mt][kk], __builtin_bit_cast(bf16x8, hb[kk][nt]),
                        acc[mt][nt], 0, 0, 0);

        // ---- WAR barrier: prior step's gate reads done before red overwrite
        __syncthreads();

        // partials -> LDS. C/D layout: col = lane&15 (batch), row = quad*4+reg.
        #pragma unroll
        for (int mt = 0; mt < 2; ++mt)
            #pragma unroll
            for (int nt = 0; nt < 4; ++nt) {
                const int row0 = mt * 16 + quad * 4;
                const int col  = nt * 16 + l15;
                *(f32x4*)&red[w][col][row0] = acc[mt][nt];
            }
        __syncthreads();

        // ---- gate phase
        float h0v, h1v;
        {
            float z0[4], z1[4];
            #pragma unroll
            for (int gate = 0; gate < 4; ++gate) {
                const int row = gate * 8 + cu;
                f32x2 s0 = *(const f32x2*)&red[0][cb][row];
                f32x2 s1 = *(const f32x2*)&red[1][cb][row];
                f32x2 s2 = *(const f32x2*)&red[2][cb][row];
                f32x2 s3 = *(const f32x2*)&red[3][cb][row];
                z0[gate] = s0[0] + s1[0] + s2[0] + s3[0] + bias0[gate];
                z1[gate] = s0[1] + s1[1] + s2[1] + s3[1] + bias1[gate];
            }
            float ig = sigmoid_f(z0[0]), fg = sigmoid_f(z0[1]);
            float gg = tanh_f(z0[2]),    og = sigmoid_f(z0[3]);
            c0v = fg * c0v + ig * gg;
            h0v = og * tanh_f(c0v);
            ig = sigmoid_f(z1[0]); fg = sigmoid_f(z1[1]);
            gg = tanh_f(z1[2]);    og = sigmoid_f(z1[3]);
            c1v = fg * c1v + ig * gg;
            h1v = og * tanh_f(c1v);
        }

        // ---- publish h_{t+1}: packed sc1 store (256B contiguous per wave),
        // wave-level drain, per-wave flag. No fences.
        {
            bf16x2 hv; hv[0] = (__bf16)h0v; hv[1] = (__bf16)h1v;
            unsigned hbits = __builtin_bit_cast(unsigned, hv);
            const __bf16* dst = hbuf + (size_t)((t + 1) & 1) * (NB * HID) + hstore_off;
            asm volatile("global_store_dword %0, %1, off sc1"
                         :: "v"(dst), "v"(hbits) : "memory");
        }
        if (t == L_STEPS - 1) {
            const int idx = cb * HID + hbase + cu;
            out[65536 + idx]      = h0v;
            out[65536 + idx + 1]  = h1v;
            out[131072 + idx]     = c0v;
            out[131072 + idx + 1] = c1v;
        }
        asm volatile("s_waitcnt vmcnt(0)" ::: "memory");
        if (lane == 0)
            __hip_atomic_store(&bar[blockIdx.x * 4 + w], (unsigned)(t + 1),
                               __ATOMIC_RELAXED, __HIP_MEMORY_SCOPE_AGENT);

        // ---- x half for t+1 (off the inter-WG critical path)
        #pragma unroll
        for (int mt = 0; mt < 2; ++mt)
            #pragma unroll
            for (int nt = 0; nt < 4; ++nt) { f32x4 z = {0.f,0.f,0.f,0.f}; acc[mt][nt] = z; }
        if (t < L_STEPS - 1)
            mfma_x(xbf + (size_t)(t + 1) * (NB * HID) + lane_off, wfx, acc);
    }
}

__global__ void out_kernel(const float* __restrict__ base, const float* __restrict__ Wout,
                           const float* __restrict__ bout, float* __restrict__ y)
{
    const int wv   = (int)((blockIdx.x * 256u + threadIdx.x) >> 6);
    const int lane = threadIdx.x & 63;
    const int b = wv >> 10;
    const int i = wv & 1023;
    const f32x4* hp = (const f32x4*)(base + 65536 + b * HID);
    const f32x4* wp = (const f32x4*)(Wout + (size_t)i * HID);
    float acc = 0.f;
    #pragma unroll
    for (int q = 0; q < 4; ++q) {
        f32x4 hv = hp[q * 64 + lane];
        f32x4 wvv = wp[q * 64 + lane];
        acc += hv[0]*wvv[0] + hv[1]*wvv[1] + hv[2]*wvv[2] + hv[3]*wvv[3];
    }
    #pragma unroll
    for (int off = 32; off > 0; off >>= 1) acc += __shfl_down(acc, off);
    if (lane == 0) y[b * HID + i] = acc + bout[i];
}

extern "C" void kernel_launch(void* const* d_in, const int* in_sizes, int n_in,
                              void* d_out, int out_size, void* d_ws, size_t ws_size,
                              hipStream_t stream)
{
    const float* x    = (const float*)d_in[0];
    const float* h0   = (const float*)d_in[1];
    const float* c0   = (const float*)d_in[2];
    const float* W_ih = (const float*)d_in[3];
    const float* W_hh = (const float*)d_in[4];
    const float* b_ih = (const float*)d_in[5];
    const float* b_hh = (const float*)d_in[6];
    const float* Wout = (const float*)d_in[7];
    const float* bout = (const float*)d_in[8];
    float* out = (float*)d_out;

    char* ws = (char*)d_ws;
    __bf16* xbf   = (__bf16*)(ws);                         // 67,108,864 B packed
    __bf16* hbuf  = (__bf16*)(ws + 67108864);              // 262,144 B packed x2
    unsigned* bar = (unsigned*)(ws + 67108864 + 262144);   // 2,048 B

    convert_kernel<<<16384, 256, 0, stream>>>(x, h0, xbf, hbuf, bar);
    lstm_kernel<<<GRID_LSTM, 256, 0, stream>>>(c0, W_ih, W_hh, b_ih, b_hh,
                                               xbf, hbuf, bar, out);
    out_kernel<<<16384, 256, 0, stream>>>(out, Wout, bout, out);
}

// Round 5
// 2918.139 us; speedup vs baseline: 3.8113x; 1.0329x over previous
//
#include <hip/hip_runtime.h>
#include <hip/hip_bf16.h>

// LSTM: L=512 steps, N=64 batch, I=H=1024.
// Round 5: ROLLING h buffer (513 slots x 128KB, one per step, no address
// reuse). h stores remain sc1 (write-through to coherence point); h loads
// become PLAIN L2-cached loads -- safe because every slot line is cold in
// every L2 until after its flag is posted (single-writer, write-once).
// This dedupes the h broadcast through each XCD's L2: fabric traffic
// 16 MB/step -> 1 MB/step, and h-load latency ~900 -> ~250 cyc for 15/16 WGs.
// Fallback: if ws_size can't fit the ring, template switch to the round-4
// double-buffer + sc1-load scheme (identical math, proven).
//  K1: convert x fp32->bf16 packed + h0 packed to slot 0 + flag init.
//  K2: persistent recurrence, 128 WGs x 256 thr: register-resident weights
//      (128 VGPR/wave), per-wave producer-subset flag polling, zero fences.
//  K3: y = h @ W_out^T + b_out.
// Packed slab layout [64 x 1024]: elem(row,col) -> byte (col>>3)*1024 + row*16 + (col&7)*2

#define L_STEPS 512
#define NB 64
#define HID 1024
#define GRID_LSTM 128

typedef __bf16 bf16x8 __attribute__((ext_vector_type(8)));
typedef __bf16 bf16x4 __attribute__((ext_vector_type(4)));
typedef __bf16 bf16x2 __attribute__((ext_vector_type(2)));
typedef float  f32x4  __attribute__((ext_vector_type(4)));
typedef float  f32x2  __attribute__((ext_vector_type(2)));
typedef unsigned u32x4 __attribute__((ext_vector_type(4)));

__device__ __forceinline__ float sigmoid_f(float x) {
    return 1.f / (1.f + __expf(-x));
}
__device__ __forceinline__ float tanh_f(float x) {
    return 1.f - 2.f / (1.f + __expf(2.f * x));
}

__global__ void convert_kernel(const float* __restrict__ x, const float* __restrict__ h0,
                               __bf16* __restrict__ xbf, __bf16* __restrict__ hbf,
                               unsigned* __restrict__ bar) {
    unsigned u = blockIdx.x * 256u + threadIdx.x;
    if (u < 512u) bar[u] = 0u;
    const int row = u & 63;
    const int cg  = (u >> 6) & 127;
    if (u < 8192u) {   // h0 -> packed slot 0
        const float* s = h0 + (size_t)row * HID + cg * 8;
        f32x4 a = *(const f32x4*)s, b = *(const f32x4*)(s + 4);
        bf16x8 o;
        o[0]=(__bf16)a[0]; o[1]=(__bf16)a[1]; o[2]=(__bf16)a[2]; o[3]=(__bf16)a[3];
        o[4]=(__bf16)b[0]; o[5]=(__bf16)b[1]; o[6]=(__bf16)b[2]; o[7]=(__bf16)b[3];
        ((bf16x8*)hbf)[u] = o;
    }
    const int t = u >> 13;
    const float* s = x + ((size_t)t * NB + row) * HID + cg * 8;
    f32x4 a = *(const f32x4*)s, b = *(const f32x4*)(s + 4);
    bf16x8 o;
    o[0]=(__bf16)a[0]; o[1]=(__bf16)a[1]; o[2]=(__bf16)a[2]; o[3]=(__bf16)a[3];
    o[4]=(__bf16)b[0]; o[5]=(__bf16)b[1]; o[6]=(__bf16)b[2]; o[7]=(__bf16)b[3];
    ((bf16x8*)xbf)[u] = o;
}

// x half-phase on a packed slab. Frag (kk,nt) = act + kk*2048 + nt*128.
__device__ __forceinline__ void mfma_x(const __bf16* __restrict__ act,
                                       const bf16x8 (&wfr)[2][8],
                                       f32x4 (&acc)[2][4]) {
    #pragma unroll
    for (int kk = 0; kk < 8; ++kk) {
        bf16x8 bfr[4];
        #pragma unroll
        for (int nt = 0; nt < 4; ++nt)
            bfr[nt] = *(const bf16x8*)(act + kk * 2048 + nt * 128);
        #pragma unroll
        for (int mt = 0; mt < 2; ++mt)
            #pragma unroll
            for (int nt = 0; nt < 4; ++nt)
                acc[mt][nt] = __builtin_amdgcn_mfma_f32_16x16x32_bf16(
                    wfr[mt][kk], bfr[nt], acc[mt][nt], 0, 0, 0);
    }
}

template <bool RING>
__global__ __launch_bounds__(256, 1) void lstm_kernel(
    const float* __restrict__ c0,
    const float* __restrict__ W_ih, const float* __restrict__ W_hh,
    const float* __restrict__ b_ih, const float* __restrict__ b_hh,
    const __bf16* __restrict__ xbf,      // [512] packed 64x1024 slabs
    __bf16* hbuf,                        // RING: [513] slots, else [2] parity
    unsigned* bar,                       // [512] per-wave step flags (wg*4+w)
    float* __restrict__ out)             // d_out: y[65536], h[65536], c[65536]
{
    const int tid  = threadIdx.x;
    const int lane = tid & 63;
    const int w    = tid >> 6;           // wave id: combined-K quarter
    const int quad = lane >> 4;
    const int l15  = lane & 15;
    const int hbase = blockIdx.x * 8;

    __shared__ float red[4][64][44];     // [wave][batch][row pad 32->44] = 45056 B

    // ---- weight preload (once, from row-major fp32 W).
    bf16x8 wfx[2][8], wfh[2][8];
    #pragma unroll
    for (int mt = 0; mt < 2; ++mt) {
        const int n    = mt * 16 + l15;
        const int grow = (n >> 3) * HID + hbase + (n & 7);
        #pragma unroll
        for (int kk = 0; kk < 8; ++kk) {
            const int kcol = w * 256 + kk * 32 + quad * 8;
            {
                const float* src = W_ih + (size_t)grow * 1024 + kcol;
                f32x4 a = *(const f32x4*)src;
                f32x4 b = *(const f32x4*)(src + 4);
                bf16x8 f;
                f[0]=(__bf16)a[0]; f[1]=(__bf16)a[1]; f[2]=(__bf16)a[2]; f[3]=(__bf16)a[3];
                f[4]=(__bf16)b[0]; f[5]=(__bf16)b[1]; f[6]=(__bf16)b[2]; f[7]=(__bf16)b[3];
                wfx[mt][kk] = f;
            }
            {
                const float* src = W_hh + (size_t)grow * 1024 + kcol;
                f32x4 a = *(const f32x4*)src;
                f32x4 b = *(const f32x4*)(src + 4);
                bf16x8 f;
                f[0]=(__bf16)a[0]; f[1]=(__bf16)a[1]; f[2]=(__bf16)a[2]; f[3]=(__bf16)a[3];
                f[4]=(__bf16)b[0]; f[5]=(__bf16)b[1]; f[6]=(__bf16)b[2]; f[7]=(__bf16)b[3];
                wfh[mt][kk] = f;
            }
        }
    }

    // per-thread cell state: pairs (cb, cu) and (cb, cu+1)
    const int p0 = tid * 2;
    const int cb = p0 >> 3;
    const int cu = p0 & 7;
    float c0v = c0[cb * HID + hbase + cu];
    float c1v = c0[cb * HID + hbase + cu + 1];

    float bias0[4], bias1[4];
    #pragma unroll
    for (int gate = 0; gate < 4; ++gate) {
        int gr = gate * HID + hbase + cu;
        bias0[gate] = b_ih[gr] + b_hh[gr];
        bias1[gate] = b_ih[gr + 1] + b_hh[gr + 1];
    }

    // per-lane packed-slab offset (elements)
    const int lane_off = (32 * w + quad) * 512 + l15 * 8;
    // packed h store offset (elements): cg = blockIdx, row = cb, col&7 = cu
    const int hstore_off = blockIdx.x * 512 + cb * 8 + cu;

    // prologue: x-partials for t=0
    f32x4 acc[2][4];
    #pragma unroll
    for (int mt = 0; mt < 2; ++mt)
        #pragma unroll
        for (int nt = 0; nt < 4; ++nt) { f32x4 z = {0.f,0.f,0.f,0.f}; acc[mt][nt] = z; }
    mfma_x(xbf + lane_off, wfx, acc);

    // producer flag set: WGs [32w, 32w+32) x 4 waves => flags [128w, 128w+128)
    const int pf0 = 128 * w + lane;
    const int pf1 = 128 * w + 64 + lane;

    for (int t = 0; t < L_STEPS; ++t) {
        // ---- per-wave wait for h_t producers (relaxed polls, no fences)
        for (;;) {
            unsigned f0 = __hip_atomic_load(&bar[pf0], __ATOMIC_RELAXED,
                                            __HIP_MEMORY_SCOPE_AGENT);
            unsigned f1 = __hip_atomic_load(&bar[pf1], __ATOMIC_RELAXED,
                                            __HIP_MEMORY_SCOPE_AGENT);
            if (__all((f0 >= (unsigned)t) && (f1 >= (unsigned)t))) break;
            __builtin_amdgcn_s_sleep(1);
        }

        // ---- h half: 32 fragment loads (1KB contiguous each).
        // RING: plain loads, slot t (cold lines -> L2-dedup per XCD).
        // else: sc1 loads, parity slot (coherence-point reads).
        u32x4 hb[8][4];
        const __bf16* hb_base = hbuf
            + (size_t)(RING ? t : (t & 1)) * (NB * HID) + lane_off;
        #pragma unroll
        for (int kk = 0; kk < 8; ++kk)
            #pragma unroll
            for (int nt = 0; nt < 4; ++nt) {
                const __bf16* p = hb_base + kk * 2048 + nt * 128;
                if constexpr (RING)
                    asm volatile("global_load_dwordx4 %0, %1, off"
                                 : "=v"(hb[kk][nt]) : "v"(p));
                else
                    asm volatile("global_load_dwordx4 %0, %1, off sc1"
                                 : "=v"(hb[kk][nt]) : "v"(p));
            }
        // group 1: wait first 16 loads (kk 0..3), MFMA while rest streams
        asm volatile("s_waitcnt vmcnt(16)"
            : "+v"(hb[0][0]), "+v"(hb[0][1]), "+v"(hb[0][2]), "+v"(hb[0][3]),
              "+v"(hb[1][0]), "+v"(hb[1][1]), "+v"(hb[1][2]), "+v"(hb[1][3]),
              "+v"(hb[2][0]), "+v"(hb[2][1]), "+v"(hb[2][2]), "+v"(hb[2][3]),
              "+v"(hb[3][0]), "+v"(hb[3][1]), "+v"(hb[3][2]), "+v"(hb[3][3]));
        #pragma unroll
        for (int kk = 0; kk < 4; ++kk)
            #pragma unroll
            for (int mt = 0; mt < 2; ++mt)
                #pragma unroll
                for (int nt = 0; nt < 4; ++nt)
                    acc[mt][nt] = __builtin_amdgcn_mfma_f32_16x16x32_bf16(
                        wfh[mt][kk], __builtin_bit_cast(bf16x8, hb[kk][nt]),
                        acc[mt][nt], 0, 0, 0);
        asm volatile("s_waitcnt vmcnt(0)"
            : "+v"(hb[4][0]), "+v"(hb[4][1]), "+v"(hb[4][2]), "+v"(hb[4][3]),
              "+v"(hb[5][0]), "+v"(hb[5][1]), "+v"(hb[5][2]), "+v"(hb[5][3]),
              "+v"(hb[6][0]), "+v"(hb[6][1]), "+v"(hb[6][2]), "+v"(hb[6][3]),
              "+v"(hb[7][0]), "+v"(hb[7][1]), "+v"(hb[7][2]), "+v"(hb[7][3]));
        #pragma unroll
        for (int kk = 4; kk < 8; ++kk)
            #pragma unroll
            for (int mt = 0; mt < 2; ++mt)
                #pragma unroll
                for (int nt = 0; nt < 4; ++nt)
                    acc[mt][nt] = __builtin_amdgcn_mfma_f32_16x16x32_bf16(
                        wfh[mt][kk], __builtin_bit_cast(bf16x8, hb[kk][nt]),
                        acc[mt][nt], 0, 0, 0);

        // ---- WAR barrier: prior step's gate reads done before red overwrite
        __syncthreads();

        // partials -> LDS. C/D layout: col = lane&15 (batch), row = quad*4+reg.
        #pragma unroll
        for (int mt = 0; mt < 2; ++mt)
            #pragma unroll
            for (int nt = 0; nt < 4; ++nt) {
                const int row0 = mt * 16 + quad * 4;
                const int col  = nt * 16 + l15;
                *(f32x4*)&red[w][col][row0] = acc[mt][nt];
            }
        __syncthreads();

        // ---- gate phase
        float h0v, h1v;
        {
            float z0[4], z1[4];
            #pragma unroll
            for (int gate = 0; gate < 4; ++gate) {
                const int row = gate * 8 + cu;
                f32x2 s0 = *(const f32x2*)&red[0][cb][row];
                f32x2 s1 = *(const f32x2*)&red[1][cb][row];
                f32x2 s2 = *(const f32x2*)&red[2][cb][row];
                f32x2 s3 = *(const f32x2*)&red[3][cb][row];
                z0[gate] = s0[0] + s1[0] + s2[0] + s3[0] + bias0[gate];
                z1[gate] = s0[1] + s1[1] + s2[1] + s3[1] + bias1[gate];
            }
            float ig = sigmoid_f(z0[0]), fg = sigmoid_f(z0[1]);
            float gg = tanh_f(z0[2]),    og = sigmoid_f(z0[3]);
            c0v = fg * c0v + ig * gg;
            h0v = og * tanh_f(c0v);
            ig = sigmoid_f(z1[0]); fg = sigmoid_f(z1[1]);
            gg = tanh_f(z1[2]);    og = sigmoid_f(z1[3]);
            c1v = fg * c1v + ig * gg;
            h1v = og * tanh_f(c1v);
        }

        // ---- publish h_{t+1}: sc1 store (write-through to coherence point),
        // wave-level drain, per-wave flag. No fences.
        {
            bf16x2 hv; hv[0] = (__bf16)h0v; hv[1] = (__bf16)h1v;
            unsigned hbits = __builtin_bit_cast(unsigned, hv);
            const __bf16* dst = hbuf
                + (size_t)(RING ? (t + 1) : ((t + 1) & 1)) * (NB * HID) + hstore_off;
            asm volatile("global_store_dword %0, %1, off sc1"
                         :: "v"(dst), "v"(hbits) : "memory");
        }
        if (t == L_STEPS - 1) {
            const int idx = cb * HID + hbase + cu;
            out[65536 + idx]      = h0v;
            out[65536 + idx + 1]  = h1v;
            out[131072 + idx]     = c0v;
            out[131072 + idx + 1] = c1v;
        }
        asm volatile("s_waitcnt vmcnt(0)" ::: "memory");
        if (lane == 0)
            __hip_atomic_store(&bar[blockIdx.x * 4 + w], (unsigned)(t + 1),
                               __ATOMIC_RELAXED, __HIP_MEMORY_SCOPE_AGENT);

        // ---- x half for t+1 (off the inter-WG critical path)
        #pragma unroll
        for (int mt = 0; mt < 2; ++mt)
            #pragma unroll
            for (int nt = 0; nt < 4; ++nt) { f32x4 z = {0.f,0.f,0.f,0.f}; acc[mt][nt] = z; }
        if (t < L_STEPS - 1)
            mfma_x(xbf + (size_t)(t + 1) * (NB * HID) + lane_off, wfx, acc);
    }
}

__global__ void out_kernel(const float* __restrict__ base, const float* __restrict__ Wout,
                           const float* __restrict__ bout, float* __restrict__ y)
{
    const int wv   = (int)((blockIdx.x * 256u + threadIdx.x) >> 6);
    const int lane = threadIdx.x & 63;
    const int b = wv >> 10;
    const int i = wv & 1023;
    const f32x4* hp = (const f32x4*)(base + 65536 + b * HID);
    const f32x4* wp = (const f32x4*)(Wout + (size_t)i * HID);
    float acc = 0.f;
    #pragma unroll
    for (int q = 0; q < 4; ++q) {
        f32x4 hv = hp[q * 64 + lane];
        f32x4 wvv = wp[q * 64 + lane];
        acc += hv[0]*wvv[0] + hv[1]*wvv[1] + hv[2]*wvv[2] + hv[3]*wvv[3];
    }
    #pragma unroll
    for (int off = 32; off > 0; off >>= 1) acc += __shfl_down(acc, off);
    if (lane == 0) y[b * HID + i] = acc + bout[i];
}

extern "C" void kernel_launch(void* const* d_in, const int* in_sizes, int n_in,
                              void* d_out, int out_size, void* d_ws, size_t ws_size,
                              hipStream_t stream)
{
    const float* x    = (const float*)d_in[0];
    const float* h0   = (const float*)d_in[1];
    const float* c0   = (const float*)d_in[2];
    const float* W_ih = (const float*)d_in[3];
    const float* W_hh = (const float*)d_in[4];
    const float* b_ih = (const float*)d_in[5];
    const float* b_hh = (const float*)d_in[6];
    const float* Wout = (const float*)d_in[7];
    const float* bout = (const float*)d_in[8];
    float* out = (float*)d_out;

    // ws layout: xbf (64 MB) | hbuf (ring: 513 slots = 64.1 MB, else 256 KB) | bar
    const size_t XBF_B  = 67108864;                  // 512 x 131072
    const size_t RING_B = 513ull * 131072;           // 67,239,936
    const size_t need_ring = XBF_B + RING_B + 2048;
    const bool ring = ws_size >= need_ring;

    char* ws = (char*)d_ws;
    __bf16* xbf   = (__bf16*)(ws);
    __bf16* hbuf  = (__bf16*)(ws + XBF_B);
    unsigned* bar = (unsigned*)(ws + XBF_B + (ring ? RING_B : 262144));

    convert_kernel<<<16384, 256, 0, stream>>>(x, h0, xbf, hbuf, bar);
    if (ring)
        lstm_kernel<true><<<GRID_LSTM, 256, 0, stream>>>(c0, W_ih, W_hh, b_ih, b_hh,
                                                         xbf, hbuf, bar, out);
    else
        lstm_kernel<false><<<GRID_LSTM, 256, 0, stream>>>(c0, W_ih, W_hh, b_ih, b_hh,
                                                          xbf, hbuf, bar, out);
    out_kernel<<<16384, 256, 0, stream>>>(out, Wout, bout, out);
}